// Round 5
// baseline (40.007 us; speedup 1.0000x reference)
//
#include <hip/hip_runtime.h>
#include <cfloat>
#include <climits>

#define B_   8
#define N1_  1024
#define N2_  4096
#define C_   256
#define NSL  8                   // candidate slices (waves) per knn block
#define SLC  (N1_ / NSL)         // 128 candidates per slice

// ---------------------------------------------------------------------------
// Kernel 0: pack candidate table T[b*N1+n] = {2x, 2y, 2z, |p1|^2}.
// Pre-doubling is exact under RN; s1 uses the reference's (xx+yy)+zz order.
// ---------------------------------------------------------------------------
__global__ __launch_bounds__(64) void prep_kernel(
    const float* __restrict__ p1, float4* __restrict__ T) {
    const int i = blockIdx.x * 64 + threadIdx.x;   // 0 .. B*N1-1
    const float x = p1[3 * (size_t)i + 0];
    const float y = p1[3 * (size_t)i + 1];
    const float z = p1[3 * (size_t)i + 2];
    const float s1 = __fadd_rn(__fadd_rn(__fmul_rn(x, x), __fmul_rn(y, y)),
                               __fmul_rn(z, z));
    T[i] = make_float4(x + x, y + y, z + z, s1);
}

// ---------------------------------------------------------------------------
// Kernel 1 (v4): 3-NN, scalar-fed. One query per LANE; candidates are
// wave-uniform -> s_load (SMEM) + 1-SGPR VALU operands. Hot loop has zero
// LDS / zero vector-memory. 8 waves/block scan disjoint 128-cand slices of
// the same 64 queries; partial top-3s merge via LDS, lexicographic (d, idx).
// Arithmetic bit-identical to reference:
//   dd = (s2 - dot2) + s1,  dot2 = (x2*2x + y2*2y) + z2*2z  ( == 2*dot )
// ---------------------------------------------------------------------------

__device__ __forceinline__ void ins_lex_(float pd, int pi,
                                         float& d0, float& d1, float& d2,
                                         int& i0, int& i1, int& i2) {
    bool l0 = (pd < d0) || (pd == d0 && pi < i0);
    bool l1 = (pd < d1) || (pd == d1 && pi < i1);
    bool l2 = (pd < d2) || (pd == d2 && pi < i2);
    float e0 = l0 ? pd : d0;
    float e1 = l1 ? (l0 ? d0 : pd) : d1;
    float e2 = l2 ? (l1 ? d1 : pd) : d2;
    int   f0 = l0 ? pi : i0;
    int   f1 = l1 ? (l0 ? i0 : pi) : i1;
    int   f2 = l2 ? (l1 ? i1 : pi) : i2;
    d0 = e0; d1 = e1; d2 = e2; i0 = f0; i1 = f1; i2 = f2;
}

__device__ __forceinline__ void ins_scan_(float dd, int n,
                                          float& d0, float& d1, float& d2,
                                          int& i0, int& i1, int& i2) {
    bool c0 = dd < d0;
    bool c1 = dd < d1;
    bool c2 = dd < d2;
    float n0 = fminf(dd, d0);
    float n1 = __builtin_amdgcn_fmed3f(dd, d0, d1);
    float n2 = __builtin_amdgcn_fmed3f(dd, d1, d2);
    int ta = c0 ? i0 : n;
    int j0 = c0 ? n  : i0;
    int j1 = c1 ? ta : i1;
    int tb = c1 ? i1 : n;
    int j2 = c2 ? tb : i2;
    d0 = n0; d1 = n1; d2 = n2;
    i0 = j0; i1 = j1; i2 = j2;
}

__global__ __launch_bounds__(64 * NSL) void knn_kernel(
    const float4* __restrict__ T, const float* __restrict__ p2,
    int4* __restrict__ wsi, float4* __restrict__ wsw) {
    __shared__ float Md[NSL][64][3];
    __shared__ int   Mi[NSL][64][3];

    const int b      = blockIdx.x >> 6;      // 64 query-tiles per batch
    const int mtile  = blockIdx.x & 63;
    const int lane   = threadIdx.x & 63;
    const int wslice = threadIdx.x >> 6;     // 0..NSL-1, wave-uniform
    const int m      = mtile * 64 + lane;

    const size_t pbase = ((size_t)b * N2_ + m) * 3;
    const float x2 = p2[pbase + 0];
    const float y2 = p2[pbase + 1];
    const float z2 = p2[pbase + 2];
    const float s2 = __fadd_rn(__fadd_rn(__fmul_rn(x2, x2), __fmul_rn(y2, y2)),
                               __fmul_rn(z2, z2));

    float d0 = FLT_MAX, d1 = FLT_MAX, d2 = FLT_MAX;
    int   i0 = INT_MAX, i1 = INT_MAX, i2 = INT_MAX;

    // Uniform base: blockIdx/wave-derived only -> scalar loads in the loop.
    const float4* Tb = T + (size_t)b * N1_ + (size_t)wslice * SLC;
    const int nbase = wslice * SLC;

#pragma unroll 8
    for (int n = 0; n < SLC; ++n) {
        const float4 c = Tb[n];              // wave-uniform -> s_load
        float t1 = __fmul_rn(x2, c.x);
        float t2 = __fmul_rn(y2, c.y);
        float t3 = __fmul_rn(z2, c.z);
        float dot2 = __fadd_rn(__fadd_rn(t1, t2), t3);   // == 2*dot exactly
        float dd = __fadd_rn(__fsub_rn(s2, dot2), c.w);
        ins_scan_(dd, nbase + n, d0, d1, d2, i0, i1, i2);
    }

    Md[wslice][lane][0] = d0; Mi[wslice][lane][0] = i0;
    Md[wslice][lane][1] = d1; Mi[wslice][lane][1] = i1;
    Md[wslice][lane][2] = d2; Mi[wslice][lane][2] = i2;
    __syncthreads();

    if (wslice == 0) {   // wave 0 merges (its own slice-0 triple is in regs)
#pragma unroll
        for (int ws = 1; ws < NSL; ++ws)
#pragma unroll
            for (int k = 0; k < 3; ++k)
                ins_lex_(Md[ws][lane][k], Mi[ws][lane][k],
                         d0, d1, d2, i0, i1, i2);

        float r0 = 1.0f / __fadd_rn(d0, 1e-8f);
        float r1 = 1.0f / __fadd_rn(d1, 1e-8f);
        float r2 = 1.0f / __fadd_rn(d2, 1e-8f);
        float s  = __fadd_rn(__fadd_rn(r0, r1), r2);
        const size_t o = (size_t)b * N2_ + m;
        wsi[o] = make_int4(i0, i1, i2, 0);
        wsw[o] = make_float4(r0 / s, r1 / s, r2 / s, 0.0f);
    }
}

// ---------------------------------------------------------------------------
// Kernel 2: gather + blend — REVERTED to the round-2/3 version (measured
// best; control variable).
// ---------------------------------------------------------------------------

__global__ __launch_bounds__(256) void blend_kernel(
    const float* __restrict__ x1, const int4* __restrict__ wsi,
    const float4* __restrict__ wsw, float* __restrict__ out) {
    __shared__ float L[4][N1_];   // 16 KB

    int bid = blockIdx.x;
    const int mhalf = bid & 1;
    const int ct    = (bid >> 1) & 63;   // 64 channel tiles of 4
    const int b     = bid >> 7;
    const int tid   = threadIdx.x;

    const float* src = x1 + ((size_t)b * C_ + ct * 4) * N1_;
    float4* Lv = reinterpret_cast<float4*>(&L[0][0]);
    const float4* Sv = reinterpret_cast<const float4*>(src);
#pragma unroll
    for (int j = 0; j < 4; ++j) Lv[tid + 256 * j] = Sv[tid + 256 * j];
    __syncthreads();

    const size_t wbase = (size_t)b * N2_;
    const size_t obase = ((size_t)b * C_ + (size_t)ct * 4) * N2_;

#pragma unroll
    for (int mb = 0; mb < 8; ++mb) {
        const int m = mhalf * 2048 + mb * 256 + tid;
        const int4   id = wsi[wbase + m];
        const float4 w  = wsw[wbase + m];
#pragma unroll
        for (int r = 0; r < 4; ++r) {
            float a  = L[r][id.x];
            float bb = L[r][id.y];
            float cc = L[r][id.z];
            float acc = __fadd_rn(__fadd_rn(__fmul_rn(a,  w.x),
                                            __fmul_rn(bb, w.y)),
                                  __fmul_rn(cc, w.z));
            __builtin_nontemporal_store(acc, &out[obase + (size_t)r * N2_ + m]);
        }
    }
}

extern "C" void kernel_launch(void* const* d_in, const int* in_sizes, int n_in,
                              void* d_out, int out_size, void* d_ws, size_t ws_size,
                              hipStream_t stream) {
    const float* p1 = (const float*)d_in[0];   // [B, N1, 3]
    const float* x1 = (const float*)d_in[1];   // [B, C, N1]
    const float* p2 = (const float*)d_in[2];   // [B, N2, 3]
    float* out = (float*)d_out;                // [B, C, N2]

    int4*   wsi = (int4*)d_ws;                                        // 512 KB
    float4* wsw = (float4*)((char*)d_ws + (size_t)B_ * N2_ * 16);     // 512 KB
    float4* T   = (float4*)((char*)d_ws + (size_t)B_ * N2_ * 32);     // 128 KB

    prep_kernel<<<B_ * N1_ / 64, 64, 0, stream>>>(p1, T);
    knn_kernel<<<B_ * (N2_ / 64), 64 * NSL, 0, stream>>>(T, p2, wsi, wsw);
    blend_kernel<<<B_ * (C_ / 4) * 2, 256, 0, stream>>>(x1, wsi, wsw, out);
}

// Round 6
// 33.068 us; speedup vs baseline: 1.2098x; 1.2098x over previous
//
#include <hip/hip_runtime.h>
#include <cfloat>
#include <climits>

#define B_   8
#define N1_  1024
#define N2_  4096
#define C_   256
#define TPQ  16                 // threads per query
#define QPB  (256 / TPQ)        // 16 queries per block

// ---------------------------------------------------------------------------
// Kernel 1: 3-NN search — byte-exact round-2 version (measured best, 33.1).
// ---------------------------------------------------------------------------

__device__ __forceinline__ bool better_(float d, int i, float D, int I) {
    return (d < D) || (d == D && i < I);   // lexicographic (d, index)
}

__device__ __forceinline__ void ins_(float d, int i,
                                     float& d0, float& d1, float& d2,
                                     int& i0, int& i1, int& i2) {
    if (better_(d, i, d2, i2)) {
        d2 = d; i2 = i;
        if (better_(d2, i2, d1, i1)) {
            float td = d1; d1 = d2; d2 = td;
            int   ti = i1; i1 = i2; i2 = ti;
            if (better_(d1, i1, d0, i0)) {
                td = d0; d0 = d1; d1 = td;
                ti = i0; i0 = i1; i1 = ti;
            }
        }
    }
}

__global__ __launch_bounds__(256) void knn_kernel(
    const float* __restrict__ p1, const float* __restrict__ p2,
    int4* __restrict__ wsi, float4* __restrict__ wsw) {
    __shared__ float4 pts[N1_];   // (2x, 2y, 2z, |p1|^2): 16 KB

    const int tid   = threadIdx.x;
    const int b     = blockIdx.x >> 8;     // N2/QPB = 256 tiles per batch
    const int mtile = blockIdx.x & 255;

    for (int j = tid; j < N1_; j += 256) {
        float x = p1[((size_t)b * N1_ + j) * 3 + 0];
        float y = p1[((size_t)b * N1_ + j) * 3 + 1];
        float z = p1[((size_t)b * N1_ + j) * 3 + 2];
        float s1 = __fadd_rn(__fadd_rn(__fmul_rn(x, x), __fmul_rn(y, y)),
                             __fmul_rn(z, z));
        pts[j] = make_float4(x + x, y + y, z + z, s1);  // 2x exact
    }
    __syncthreads();

    const int q = tid >> 4;       // query within tile
    const int t = tid & 15;       // sub-thread within query
    const int m = mtile * QPB + q;

    const size_t pbase = ((size_t)b * N2_ + m) * 3;
    const float x2 = p2[pbase + 0];
    const float y2 = p2[pbase + 1];
    const float z2 = p2[pbase + 2];
    const float s2 = __fadd_rn(__fadd_rn(__fmul_rn(x2, x2), __fmul_rn(y2, y2)),
                               __fmul_rn(z2, z2));

    float d0 = FLT_MAX, d1 = FLT_MAX, d2 = FLT_MAX;
    int   i0 = INT_MAX, i1 = INT_MAX, i2 = INT_MAX;

#pragma unroll 4
    for (int n = t; n < N1_; n += TPQ) {
        float4 p = pts[n];
        // dot2 == 2*dot bit-exactly (x2 scaling commutes with RN rounding)
        float dot2 = __fadd_rn(__fadd_rn(__fmul_rn(x2, p.x), __fmul_rn(y2, p.y)),
                               __fmul_rn(z2, p.z));
        float dd = __fadd_rn(__fsub_rn(s2, dot2), p.w);

        // branchless sorted insert (strict less; ascending n => index tiebreak)
        bool c0 = dd < d0;
        bool c1 = dd < d1;
        bool c2 = dd < d2;
        float n0 = fminf(dd, d0);
        float n1 = __builtin_amdgcn_fmed3f(dd, d0, d1);  // d0<=d1 sorted
        float n2 = __builtin_amdgcn_fmed3f(dd, d1, d2);
        int j0 = c0 ? n : i0;
        int j1 = c1 ? (c0 ? i0 : n) : i1;
        int j2 = c2 ? (c1 ? i1 : n) : i2;
        d0 = n0; d1 = n1; d2 = n2;
        i0 = j0; i1 = j1; i2 = j2;
    }

    // Butterfly-merge the 16 partial lists (exact (d,i) lexicographic).
    for (int mask = 1; mask < TPQ; mask <<= 1) {
        float pd0 = __shfl_xor(d0, mask, TPQ);
        float pd1 = __shfl_xor(d1, mask, TPQ);
        float pd2 = __shfl_xor(d2, mask, TPQ);
        int   pi0 = __shfl_xor(i0, mask, TPQ);
        int   pi1 = __shfl_xor(i1, mask, TPQ);
        int   pi2 = __shfl_xor(i2, mask, TPQ);
        ins_(pd0, pi0, d0, d1, d2, i0, i1, i2);
        ins_(pd1, pi1, d0, d1, d2, i0, i1, i2);
        ins_(pd2, pi2, d0, d1, d2, i0, i1, i2);
    }

    if (t == 0) {
        float r0 = 1.0f / __fadd_rn(d0, 1e-8f);
        float r1 = 1.0f / __fadd_rn(d1, 1e-8f);
        float r2 = 1.0f / __fadd_rn(d2, 1e-8f);
        float s  = __fadd_rn(__fadd_rn(r0, r1), r2);
        const size_t o = (size_t)b * N2_ + m;
        wsi[o] = make_int4(i0, i1, i2, 0);
        wsw[o] = make_float4(r0 / s, r1 / s, r2 / s, 0.0f);
    }
}

// ---------------------------------------------------------------------------
// Kernel 2 (v4): gather + blend, channel-interleaved LDS with XOR swizzle.
//   L4[slot(n)] = {ch0[n], ch1[n], ch2[n], ch3[n]},  slot(n) = n ^ ((n>>3)&7)
// - stage writes: n = 4*lane+e -> every 8 consecutive lanes hit all 8
//   b128 bank-groups exactly once => conflict-free ds_write_b128
// - gathers: 3 random ds_read_b128 per m (was 12 random ds_read_b32)
// - wsi/wsw for all 8 m-iters prefetched before the stage (latency hidden)
// - grid/occupancy/stores identical to blend_v2 (measured best)
// ---------------------------------------------------------------------------

__global__ __launch_bounds__(256) void blend_kernel(
    const float* __restrict__ x1, const int4* __restrict__ wsi,
    const float4* __restrict__ wsw, float* __restrict__ out) {
    __shared__ float4 L4[N1_];   // 16 KB, XOR-swizzled channel-interleaved

    int bid = blockIdx.x;
    const int mhalf = bid & 1;
    const int ct    = (bid >> 1) & 63;   // 64 channel tiles of 4
    const int b     = bid >> 7;
    const int tid   = threadIdx.x;

    // Prefetch idx/weights for all 8 m-iterations.
    const size_t wbase = (size_t)b * N2_ + (size_t)mhalf * 2048;
    int4   id[8];
    float4 w[8];
#pragma unroll
    for (int mb = 0; mb < 8; ++mb) {
        id[mb] = wsi[wbase + mb * 256 + tid];
        w[mb]  = wsw[wbase + mb * 256 + tid];
    }

    // Stage 4 channels, register-transposed into interleaved LDS.
    const float* src = x1 + ((size_t)b * C_ + (size_t)ct * 4) * N1_;
    float4 v[4];
#pragma unroll
    for (int c = 0; c < 4; ++c)
        v[c] = reinterpret_cast<const float4*>(src + (size_t)c * N1_)[tid];
#pragma unroll
    for (int e = 0; e < 4; ++e) {
        const int n = 4 * tid + e;
        L4[n ^ ((n >> 3) & 7)] = make_float4((&v[0].x)[e], (&v[1].x)[e],
                                             (&v[2].x)[e], (&v[3].x)[e]);
    }
    __syncthreads();

    const size_t obase = ((size_t)b * C_ + (size_t)ct * 4) * N2_;
#pragma unroll
    for (int mb = 0; mb < 8; ++mb) {
        const int m = mhalf * 2048 + mb * 256 + tid;
        const int na = id[mb].x, nb = id[mb].y, nc = id[mb].z;
        const float4 A  = L4[na ^ ((na >> 3) & 7)];
        const float4 Bv = L4[nb ^ ((nb >> 3) & 7)];
        const float4 Cv = L4[nc ^ ((nc >> 3) & 7)];
        const float wx = w[mb].x, wy = w[mb].y, wz = w[mb].z;
#pragma unroll
        for (int r = 0; r < 4; ++r) {
            float acc = __fadd_rn(__fadd_rn(__fmul_rn((&A.x)[r],  wx),
                                            __fmul_rn((&Bv.x)[r], wy)),
                                  __fmul_rn((&Cv.x)[r], wz));
            __builtin_nontemporal_store(acc, &out[obase + (size_t)r * N2_ + m]);
        }
    }
}

extern "C" void kernel_launch(void* const* d_in, const int* in_sizes, int n_in,
                              void* d_out, int out_size, void* d_ws, size_t ws_size,
                              hipStream_t stream) {
    const float* p1 = (const float*)d_in[0];   // [B, N1, 3]
    const float* x1 = (const float*)d_in[1];   // [B, C, N1]
    const float* p2 = (const float*)d_in[2];   // [B, N2, 3]
    float* out = (float*)d_out;                // [B, C, N2]

    int4*   wsi = (int4*)d_ws;
    float4* wsw = (float4*)((char*)d_ws + (size_t)B_ * N2_ * sizeof(int4));

    knn_kernel<<<B_ * (N2_ / QPB), 256, 0, stream>>>(p1, p2, wsi, wsw);
    blend_kernel<<<B_ * (C_ / 4) * 2, 256, 0, stream>>>(x1, wsi, wsw, out);
}